// Round 5
// baseline (122.907 us; speedup 1.0000x reference)
//
#include <hip/hip_runtime.h>
#include <math.h>

typedef short bf16x8 __attribute__((ext_vector_type(8)));
typedef short s16x2  __attribute__((ext_vector_type(2)));
typedef float f32x16 __attribute__((ext_vector_type(16)));
typedef float f32x4  __attribute__((ext_vector_type(4)));
typedef float f32x2  __attribute__((ext_vector_type(2)));
typedef unsigned int u32x4 __attribute__((ext_vector_type(4)));
typedef unsigned int u32x2 __attribute__((ext_vector_type(2)));

namespace {
constexpr int kNCont = 6, kNCat = 6, kNCategories = 100;
constexpr int kQ = 12, kD = 10, kHid = 20, kD0 = 10;
constexpr int kL1 = 30, kL2 = 20, kNPairs = 78;
constexpr int kM = 32;            // batch tile per block
constexpr int kBlock = 256;       // 4 waves
constexpr int kTB = 80;           // padded pair slots for tokb table
}

// Per-wave k ownership (partition of 0..11); pair counts 19/20/20/19.
__constant__ int cKset[12] = {11, 4, 1, 10, 5, 2, 9, 8, 0, 7, 6, 3};

union ABu { u32x4 u; bf16x8 s; unsigned int w[4]; unsigned short h[8]; };
union D16 { f32x16 v; f32x4 q[4]; f32x2 d[8]; float f[16]; };
union A12 { f32x2 d[6]; float f[12]; };

__device__ __forceinline__ unsigned int fu(float x) { return __float_as_uint(x); }
__device__ __forceinline__ unsigned short f2bf_rne(float v) {
    unsigned int x = fu(v);
    return (unsigned short)((x + 0x7FFFu + ((x >> 16) & 1u)) >> 16);
}
// pack two f32 to bf16x2 by truncation: low16 = hi(e0), high16 = hi(e1)
__device__ __forceinline__ unsigned int pack_trunc(float e0, float e1) {
    return __builtin_amdgcn_perm(fu(e1), fu(e0), 0x07060302u);
}
// packed relu on a u32 holding 2 bf16: max_i16(x,0) == relu per bf16 half
__device__ __forceinline__ unsigned int pk_relu(unsigned int w) {
    s16x2 v; __builtin_memcpy(&v, &w, 4);
    const s16x2 z = {0, 0};
    v = __builtin_elementwise_max(v, z);
    unsigned int r; __builtin_memcpy(&r, &v, 4);
    return r;
}

__global__ __launch_bounds__(kBlock, 4) void pin_main(
    const float* __restrict__ x_cont,
    const int*   __restrict__ x_cat,
    const float* __restrict__ exposure,
    const float* __restrict__ cont_W1,
    const float* __restrict__ cont_b1,
    const float* __restrict__ cont_W2,
    const float* __restrict__ cont_b2,
    const float* __restrict__ cat_tables,
    const float* __restrict__ tokens,  // [78,10]
    const float* __restrict__ sW1,     // [30,30]
    const float* __restrict__ sb1,     // [30]
    const float* __restrict__ sW2,     // [30,20]
    const float* __restrict__ sb2,     // [20]
    const float* __restrict__ sW3,     // [20]
    const float* __restrict__ sb3,     // [1]
    const float* __restrict__ out_w,   // [78]
    const float* __restrict__ out_b,   // [1]
    float* __restrict__ out)
{
    // Ej d0..7 packed bf16: [q][b][4 u32], 16B lane stride (conflict-free b128).
    __shared__ __align__(16) unsigned int EldsA[kQ * kM * 4];   // 6144 B
    // Ej d8,d9 packed: [q][b] one u32, 4B lane stride.
    __shared__ __align__(16) unsigned int EldsB[kQ * kM];       // 1536 B
    // tokb = W1c@tok[p] + sb1 (+ones row), C-reg order, [ih][p][16 f32]:
    // one base per (ih,p), quadrants at +0/+16/+32/+48 bytes. 10240 B.
    __shared__ __align__(16) float Tok[2 * kTB * 16];
    __shared__ float etab[kM];
    __shared__ float etaConst;
    __shared__ unsigned int Zw[4];    // zero words for ihalf1 dummy reads

    const int tid   = threadIdx.x;
    const int lane  = tid & 63;
    const int b     = lane & 31;          // batch row / MFMA col n
    const int ihalf = lane >> 5;          // fragment k-half selector
    const int wv    = __builtin_amdgcn_readfirstlane((int)(tid >> 6));
    const int gb    = blockIdx.x * kM + b;

    if (tid < kM) etab[tid] = 0.0f;
    if (tid == 0) { Zw[0] = 0u; Zw[1] = 0u; Zw[2] = 0u; Zw[3] = 0u; }

    // ---- etaConst = out_b + sb3/6 * sum(out_w): parallel wave-0 reduce ----
    if (wv == 0) {
        float v = (lane < kNPairs) ? out_w[lane] : 0.0f;
        if (lane < kNPairs - 64) v += out_w[64 + lane];
        v += __shfl_xor(v, 1, 64);
        v += __shfl_xor(v, 2, 64);
        v += __shfl_xor(v, 4, 64);
        v += __shfl_xor(v, 8, 64);
        v += __shfl_xor(v, 16, 64);
        v += __shfl_xor(v, 32, 64);
        if (lane == 0) etaConst = out_b[0] + sb3[0] * (1.0f / 6.0f) * v;
    }

    // tau: verified r7-r10 — C-reg order <-> i order for B-frag consumption.
    const int q2  = (b >> 2) & 3;
    const int tau = b + (q2 == 1 ? 4 : (q2 == 2 ? -4 : 0));

    // ---- layer-1 A-frags, k-slot map:
    //   kstep0 slots 0..7  = Ej d0..7  -> sW1 rows 0..7
    //   kstep0 slots 8..15 = Ek d0..7  -> sW1 rows 10..17
    //   kstep1 slots 16,17 = Ej d8,d9  -> sW1 rows 8,9
    //   kstep1 slots 18,19 = Ek d8,d9  -> sW1 rows 18,19
    //   (tok + sb1 + ones-row live in the C operand via Tok) ----
    ABu wj0, wj1;
    #pragma unroll
    for (int e = 0; e < 8; ++e) {
        const int s  = 8 * ihalf + e;
        const int zd = (s < 8) ? s : s + 2;        // 0..7 -> Ej; 8..15 -> Ek d0..7
        wj0.h[e] = f2bf_rne((tau < kL1) ? sW1[zd * kL1 + tau] : 0.0f);
    }
    #pragma unroll
    for (int e = 0; e < 8; ++e) {
        float v = 0.0f;
        if (ihalf == 0 && tau < kL1) {
            if      (e == 0) v = sW1[8  * kL1 + tau];
            else if (e == 1) v = sW1[9  * kL1 + tau];
            else if (e == 2) v = sW1[18 * kL1 + tau];
            else if (e == 3) v = sW1[19 * kL1 + tau];
        }
        wj1.h[e] = f2bf_rne(v);
    }

    // ---- layer-2 A-frags (sW2 rows o=b, k-slots i; i=30 -> sb2) ----
    ABu bf0, bf1;
    #pragma unroll
    for (int e = 0; e < 8; ++e) {
        const int k0 = ihalf * 8 + e;
        const int k1 = 16 + ihalf * 8 + e;
        float v0 = 0.0f, v1 = 0.0f;
        if (b < kL2) {
            v0 = (k0 < kL1) ? sW2[k0 * kL2 + b] : (k0 == 30 ? sb2[b] : 0.0f);
            v1 = (k1 < kL1) ? sW2[k1 * kL2 + b] : (k1 == 30 ? sb2[b] : 0.0f);
        }
        bf0.h[e] = f2bf_rne(v0);
        bf1.h[e] = f2bf_rne(v1);
    }

    // ---- Phase A: E table, half-wave units (unit = 2*wv+ihalf in 0..7).
    // Units 0..5: ONE full cont MLP each. Wave 3 (units 6,7): six cat
    // gathers, 3 per half, pipelined (idx loads first, then gathers). ----
    {
        const int unit = (wv << 1) | ihalf;           // uniform per half-wave
        if (unit < kNCont) {
            const int q = unit;                        // cont feature
            const float x = x_cont[gb * kNCont + q];
            f32x2 E2[5];
            #pragma unroll
            for (int dd = 0; dd < 5; ++dd)
                E2[dd] = f32x2{cont_b2[q * kD + 2 * dd],
                               cont_b2[q * kD + 2 * dd + 1]};
            #pragma unroll 4
            for (int h = 0; h < kHid; ++h) {
                const float pre = fmaf(x, cont_W1[q * kHid + h],
                                       cont_b1[q * kHid + h]);
                const float hv  = fmaxf(pre, 0.0f);
                const f32x2 hv2 = {hv, hv};
                const float* w2 = cont_W2 + (q * kHid + h) * kD;
                #pragma unroll
                for (int dd = 0; dd < 5; ++dd)
                    E2[dd] = __builtin_elementwise_fma(
                        hv2, f32x2{w2[2 * dd], w2[2 * dd + 1]}, E2[dd]);
            }
            *(u32x4*)&EldsA[(q * kM + b) * 4] =
                u32x4{pack_trunc(E2[0].x, E2[0].y), pack_trunc(E2[1].x, E2[1].y),
                      pack_trunc(E2[2].x, E2[2].y), pack_trunc(E2[3].x, E2[3].y)};
            EldsB[q * kM + b] = pack_trunc(E2[4].x, E2[4].y);
        } else {
            const int c0 = (unit - kNCont) * 3;        // 0 or 3
            int idxs[3];
            #pragma unroll
            for (int t = 0; t < 3; ++t)
                idxs[t] = x_cat[gb * kNCat + c0 + t];   // issue all idx loads
            #pragma unroll
            for (int t = 0; t < 3; ++t) {
                const int c = c0 + t;
                const int q = kNCont + c;
                const float* src = cat_tables + (c * kNCategories + idxs[t]) * kD;
                f32x2 E2[5];
                #pragma unroll
                for (int dd = 0; dd < 5; ++dd)
                    E2[dd] = f32x2{src[2 * dd], src[2 * dd + 1]};
                *(u32x4*)&EldsA[(q * kM + b) * 4] =
                    u32x4{pack_trunc(E2[0].x, E2[0].y),
                          pack_trunc(E2[1].x, E2[1].y),
                          pack_trunc(E2[2].x, E2[2].y),
                          pack_trunc(E2[3].x, E2[3].y)};
                EldsB[q * kM + b] = pack_trunc(E2[4].x, E2[4].y);
            }
        }
    }

    // ---- tokb precompute (waves 0..2; one MFMA each covering 32 pairs):
    // tokb[p][o] = sum_i sW1[20+i][o]*tok[p][i] + sb1[o]; row(tau==30) = 1.
    // Output stored [ih][p][16] in C-reg order (quadrants contiguous). ----
    if (wv < 3) {
        const int p  = wv * 32 + b;
        const int pc = min(p, kNPairs - 1);
        const float* tp = tokens + pc * kD0;
        // ih0: d0..3 ; ih1: d6..9 (in-bounds even at pc=77; .z,.w = d8,d9)
        const f32x4 ta = *(const f32x4*)(tp + ihalf * 6);
        const f32x4 tb = *(const f32x4*)(tp + 4);      // d4..7 (ih0 only)
        const unsigned int c01 = pack_trunc(ta.x, ta.y);
        const unsigned int c23 = pack_trunc(ta.z, ta.w);
        ABu b2;
        b2.w[0] = ihalf ? c23 : c01;                   // ih1 slot8,9 = d8,d9
        b2.w[1] = ihalf ? 0x00003F80u : c23;           // ih1 slot10 = 1.0 (bias)
        b2.w[2] = ihalf ? 0u : pack_trunc(tb.x, tb.y);
        b2.w[3] = ihalf ? 0u : pack_trunc(tb.z, tb.w);
        ABu a2;
        #pragma unroll
        for (int e = 0; e < 8; ++e) {
            float v = 0.0f;
            if (ihalf == 0) {
                if (tau < kL1) v = sW1[(20 + e) * kL1 + tau];
            } else {
                if      (e == 0) { if (tau < kL1) v = sW1[28 * kL1 + tau]; }
                else if (e == 1) { if (tau < kL1) v = sW1[29 * kL1 + tau]; }
                else if (e == 2) v = (tau < kL1) ? sb1[tau]
                                                 : (tau == 30 ? 1.0f : 0.0f);
            }
            a2.h[e] = f2bf_rne(v);
        }
        f32x16 tc = {};
        tc = __builtin_amdgcn_mfma_f32_32x32x16_bf16(a2.s, b2.s, tc, 0, 0, 0);
        if (p < kNPairs) {
            D16 u; u.v = tc;
            float* dst = &Tok[(ihalf * kTB + p) * 16];
            #pragma unroll
            for (int g = 0; g < 4; ++g)
                *(f32x4*)(dst + 4 * g) = u.q[g];
        }
    }
    __syncthreads();

    // ---- Phase B: per pair
    //   d1 = mfma(wj0, [Ej07|Ek07], tokC); d1 = mfma(wj1, [Ej89,Ek89,0..], d1)
    //   hf = pk_relu(pack(d1)) -> d2 = 2 MFMAs -> relu -> out_w-weighted acc ----
    A12 acc;
    #pragma unroll
    for (int h = 0; h < 6; ++h) acc.d[h] = f32x2{0.0f, 0.0f};

    const unsigned int* e0base = EldsA + b * 4;
    const int e0stepJ = ihalf ? 0 : 128;                  // u32/j (row = 512 B)
    const unsigned int* e1base = ihalf ? Zw : (EldsB + b);
    const int e1stepJ = ihalf ? 0 : 32;                   // u32/j (row = 128 B)
    const float* tokBase = Tok + ihalf * (kTB * 16);

    #pragma unroll 1
    for (int ki = 0; ki < 3; ++ki) {
        const int k = __builtin_amdgcn_readfirstlane(cKset[wv * 3 + ki]);
        const unsigned int* pj0 = e0base + (ihalf ? k * 128 : 0);
        const unsigned int* pj1 = e1base;
        const unsigned int ekb  = *(e1base + (ihalf ? 0 : k * 32)); // hoisted /k

        int p = k;                                         // p(j=0) = k
        #pragma unroll 2
        for (int j = 0; j <= k; ++j) {
            ABu e0; e0.u = *(const u32x4*)pj0;   // ih0: Ej d0..7; ih1: Ek d0..7
            const unsigned int ejb = *pj1;       // ih0: Ej d8d9;  ih1: 0
            ABu e1; e1.u = u32x4{ejb, ekb, 0u, 0u};

            const float* tp2 = tokBase + p * 16; // quadrants at +0/+4/+8/+12
            D16 dc;
            dc.q[0] = *(const f32x4*)(tp2);
            dc.q[1] = *(const f32x4*)(tp2 + 4);
            dc.q[2] = *(const f32x4*)(tp2 + 8);
            dc.q[3] = *(const f32x4*)(tp2 + 12);

            __builtin_amdgcn_s_setprio(1);
            f32x16 d1 = dc.v;
            d1 = __builtin_amdgcn_mfma_f32_32x32x16_bf16(wj0.s, e0.s, d1, 0, 0, 0);
            d1 = __builtin_amdgcn_mfma_f32_32x32x16_bf16(wj1.s, e1.s, d1, 0, 0, 0);

            // pack raw d1, then packed-int16 relu (== relu per bf16 half)
            D16 t; t.v = d1;
            ABu hf0, hf1;                              // h1 as layer-2 B-operand
            hf0.w[0] = pk_relu(pack_trunc(t.q[0].x, t.q[0].y));
            hf0.w[1] = pk_relu(pack_trunc(t.q[0].z, t.q[0].w));
            hf0.w[2] = pk_relu(pack_trunc(t.q[1].x, t.q[1].y));
            hf0.w[3] = pk_relu(pack_trunc(t.q[1].z, t.q[1].w));
            hf1.w[0] = pk_relu(pack_trunc(t.q[2].x, t.q[2].y));
            hf1.w[1] = pk_relu(pack_trunc(t.q[2].z, t.q[2].w));
            hf1.w[2] = pk_relu(pack_trunc(t.q[3].x, t.q[3].y));
            hf1.w[3] = pk_relu(pack_trunc(t.q[3].z, t.q[3].w));

            f32x16 d2 = {};
            d2 = __builtin_amdgcn_mfma_f32_32x32x16_bf16(bf0.s, hf0.s, d2, 0, 0, 0);
            d2 = __builtin_amdgcn_mfma_f32_32x32x16_bf16(bf1.s, hf1.s, d2, 0, 0, 0);
            __builtin_amdgcn_s_setprio(0);

            // acc only regs 0..11 (regs 12..15 never read downstream);
            // f32x2 ops -> v_pk_fma_f32 on gfx950
            const float wp = out_w[p];                 // s_load
            const f32x2 wp2 = {wp, wp};
            const f32x2 z2 = {};
            D16 r2; r2.v = d2;
            #pragma unroll
            for (int h = 0; h < 6; ++h) {
                const f32x2 rr = __builtin_elementwise_max(r2.d[h], z2);
                acc.d[h] = __builtin_elementwise_fma(rr, wp2, acc.d[h]);
            }

            pj0 += e0stepJ;
            pj1 += e1stepJ;
            p   += 11 - j;                             // p(j+1) - p(j)
        }
    }

    // ---- epilogue: eta[b] = (1/6)*sum_r sW3[o_r]*acc[r] ----
    float etaL = 0.0f;
    if (ihalf == 0) {       // r=0..11 -> o = 0..3, 8..11, 16..19
        #pragma unroll
        for (int r = 0; r < 12; ++r)
            etaL = fmaf(acc.f[r], sW3[(r & 3) + 8 * (r >> 2)], etaL);
    } else {                // r=0..7 -> o = 4..7, 12..15
        #pragma unroll
        for (int r = 0; r < 8; ++r)
            etaL = fmaf(acc.f[r], sW3[(r & 3) + 8 * (r >> 2) + 4], etaL);
    }
    etaL += __shfl_xor(etaL, 32, 64);   // combine o-halves
    if (ihalf == 0) atomicAdd(&etab[b], etaL);
    __syncthreads();

    if (tid < kM) {
        float eta = etab[tid] * (1.0f / 6.0f) + etaConst;
        eta = fminf(fmaxf(eta, -20.0f), 20.0f);
        const int ob = blockIdx.x * kM + tid;
        out[ob] = __expf(eta) * exposure[ob];
    }
}

extern "C" void kernel_launch(void* const* d_in, const int* in_sizes, int n_in,
                              void* d_out, int out_size, void* d_ws, size_t ws_size,
                              hipStream_t stream) {
    (void)n_in; (void)out_size; (void)d_ws; (void)ws_size;
    const float* x_cont     = (const float*)d_in[0];
    const int*   x_cat      = (const int*)  d_in[1];
    const float* exposure   = (const float*)d_in[2];
    const float* cont_W1    = (const float*)d_in[3];
    const float* cont_b1    = (const float*)d_in[4];
    const float* cont_W2    = (const float*)d_in[5];
    const float* cont_b2    = (const float*)d_in[6];
    const float* cat_tables = (const float*)d_in[7];
    const float* tokens     = (const float*)d_in[8];
    const float* sW1        = (const float*)d_in[9];
    const float* sb1        = (const float*)d_in[10];
    const float* sW2        = (const float*)d_in[11];
    const float* sb2        = (const float*)d_in[12];
    const float* sW3        = (const float*)d_in[13];
    const float* sb3        = (const float*)d_in[14];
    const float* out_w      = (const float*)d_in[15];
    const float* out_b      = (const float*)d_in[16];

    const int B = in_sizes[2];        // exposure is [B]
    pin_main<<<B / kM, kBlock, 0, stream>>>(
        x_cont, x_cat, exposure, cont_W1, cont_b1, cont_W2, cont_b2,
        cat_tables, tokens, sW1, sb1, sW2, sb2, sW3, sb3, out_w, out_b,
        (float*)d_out);
}

// Round 6
// 120.554 us; speedup vs baseline: 1.0195x; 1.0195x over previous
//
#include <hip/hip_runtime.h>
#include <math.h>

typedef short bf16x8 __attribute__((ext_vector_type(8)));
typedef short s16x2  __attribute__((ext_vector_type(2)));
typedef float f32x16 __attribute__((ext_vector_type(16)));
typedef float f32x4  __attribute__((ext_vector_type(4)));
typedef float f32x2  __attribute__((ext_vector_type(2)));
typedef unsigned int u32x4 __attribute__((ext_vector_type(4)));
typedef unsigned int u32x2 __attribute__((ext_vector_type(2)));

namespace {
constexpr int kNCont = 6, kNCat = 6, kNCategories = 100;
constexpr int kQ = 12, kD = 10, kHid = 20, kD0 = 10;
constexpr int kL1 = 30, kL2 = 20, kNPairs = 78;
constexpr int kM = 32;            // batch tile per block
constexpr int kBlock = 256;       // 4 waves
constexpr int kTB = 80;           // padded pair slots for tokb table
// ws layout (floats): [0,1024) frags as u32x4[4][64]; [1024,3584) Tok
// [ih][p][16]; [3584] etaConst. 14340 B total.
constexpr int kWsTok = 1024;
constexpr int kWsEta = 3584;
}

// Per-wave k ownership (partition of 0..11); pair counts 19/20/20/19.
__constant__ int cKset[12] = {11, 4, 1, 10, 5, 2, 9, 8, 0, 7, 6, 3};

union ABu { u32x4 u; bf16x8 s; unsigned int w[4]; unsigned short h[8]; };
union D16 { f32x16 v; f32x4 q[4]; f32x2 d[8]; float f[16]; };
union A12 { f32x2 d[6]; float f[12]; };

__device__ __forceinline__ unsigned int fu(float x) { return __float_as_uint(x); }
__device__ __forceinline__ unsigned short f2bf_rne(float v) {
    unsigned int x = fu(v);
    return (unsigned short)((x + 0x7FFFu + ((x >> 16) & 1u)) >> 16);
}
// pack two f32 to bf16x2 by truncation: low16 = hi(e0), high16 = hi(e1)
__device__ __forceinline__ unsigned int pack_trunc(float e0, float e1) {
    return __builtin_amdgcn_perm(fu(e1), fu(e0), 0x07060302u);
}
// packed relu on a u32 holding 2 bf16: max_i16(x,0) == relu per bf16 half
__device__ __forceinline__ unsigned int pk_relu(unsigned int w) {
    s16x2 v; __builtin_memcpy(&v, &w, 4);
    const s16x2 z = {0, 0};
    v = __builtin_elementwise_max(v, z);
    unsigned int r; __builtin_memcpy(&r, &v, 4);
    return r;
}

// ---------- setup kernel: all block-invariant precompute, once ----------
__global__ __launch_bounds__(kBlock) void pin_setup(
    const float* __restrict__ tokens,  // [78,10]
    const float* __restrict__ sW1,     // [30,30]
    const float* __restrict__ sb1,     // [30]
    const float* __restrict__ sW2,     // [30,20]
    const float* __restrict__ sb2,     // [20]
    const float* __restrict__ sb3,     // [1]
    const float* __restrict__ out_w,   // [78]
    const float* __restrict__ out_b,   // [1]
    float* __restrict__ ws)
{
    const int tid   = threadIdx.x;
    const int lane  = tid & 63;
    const int b     = lane & 31;
    const int ihalf = lane >> 5;
    const int wv    = __builtin_amdgcn_readfirstlane((int)(tid >> 6));

    const int q2  = (b >> 2) & 3;
    const int tau = b + (q2 == 1 ? 4 : (q2 == 2 ? -4 : 0));

    // etaConst = out_b + sb3/6 * sum(out_w)
    if (wv == 1) {
        float v = (lane < kNPairs) ? out_w[lane] : 0.0f;
        if (lane < kNPairs - 64) v += out_w[64 + lane];
        v += __shfl_xor(v, 1, 64);
        v += __shfl_xor(v, 2, 64);
        v += __shfl_xor(v, 4, 64);
        v += __shfl_xor(v, 8, 64);
        v += __shfl_xor(v, 16, 64);
        v += __shfl_xor(v, 32, 64);
        if (lane == 0) ws[kWsEta] = out_b[0] + sb3[0] * (1.0f / 6.0f) * v;
    }

    if (wv == 0) {
        // layer-1 A-frags, k-slot map (see main kernel comment)
        ABu wj0, wj1;
        #pragma unroll
        for (int e = 0; e < 8; ++e) {
            const int s  = 8 * ihalf + e;
            const int zd = (s < 8) ? s : s + 2;
            wj0.h[e] = f2bf_rne((tau < kL1) ? sW1[zd * kL1 + tau] : 0.0f);
        }
        #pragma unroll
        for (int e = 0; e < 8; ++e) {
            float v = 0.0f;
            if (ihalf == 0 && tau < kL1) {
                if      (e == 0) v = sW1[8  * kL1 + tau];
                else if (e == 1) v = sW1[9  * kL1 + tau];
                else if (e == 2) v = sW1[18 * kL1 + tau];
                else if (e == 3) v = sW1[19 * kL1 + tau];
            }
            wj1.h[e] = f2bf_rne(v);
        }
        // layer-2 A-frags (sW2 rows o=b, k-slots i; i=30 -> sb2)
        ABu bf0, bf1;
        #pragma unroll
        for (int e = 0; e < 8; ++e) {
            const int k0 = ihalf * 8 + e;
            const int k1 = 16 + ihalf * 8 + e;
            float v0 = 0.0f, v1 = 0.0f;
            if (b < kL2) {
                v0 = (k0 < kL1) ? sW2[k0 * kL2 + b] : (k0 == 30 ? sb2[b] : 0.0f);
                v1 = (k1 < kL1) ? sW2[k1 * kL2 + b] : (k1 == 30 ? sb2[b] : 0.0f);
            }
            bf0.h[e] = f2bf_rne(v0);
            bf1.h[e] = f2bf_rne(v1);
        }
        u32x4* wsF = (u32x4*)ws;           // [frag][lane]
        wsF[0 * 64 + lane] = wj0.u;
        wsF[1 * 64 + lane] = wj1.u;
        wsF[2 * 64 + lane] = bf0.u;
        wsF[3 * 64 + lane] = bf1.u;
    }

    // tokb precompute (waves 1..3 here; one MFMA each covering 32 pairs):
    // tokb[p][o] = sum_i sW1[20+i][o]*tok[p][i] + sb1[o]; row(tau==30) = 1.
    if (wv >= 1) {
        const int p  = (wv - 1) * 32 + b;
        const int pc = min(p, kNPairs - 1);
        const float* tp = tokens + pc * kD0;
        const f32x4 ta = *(const f32x4*)(tp + ihalf * 6);
        const f32x4 tb = *(const f32x4*)(tp + 4);      // d4..7 (ih0 only)
        const unsigned int c01 = pack_trunc(ta.x, ta.y);
        const unsigned int c23 = pack_trunc(ta.z, ta.w);
        ABu b2;
        b2.w[0] = ihalf ? c23 : c01;                   // ih1 slot8,9 = d8,d9
        b2.w[1] = ihalf ? 0x00003F80u : c23;           // ih1 slot10 = 1.0 (bias)
        b2.w[2] = ihalf ? 0u : pack_trunc(tb.x, tb.y);
        b2.w[3] = ihalf ? 0u : pack_trunc(tb.z, tb.w);
        ABu a2;
        #pragma unroll
        for (int e = 0; e < 8; ++e) {
            float v = 0.0f;
            if (ihalf == 0) {
                if (tau < kL1) v = sW1[(20 + e) * kL1 + tau];
            } else {
                if      (e == 0) { if (tau < kL1) v = sW1[28 * kL1 + tau]; }
                else if (e == 1) { if (tau < kL1) v = sW1[29 * kL1 + tau]; }
                else if (e == 2) v = (tau < kL1) ? sb1[tau]
                                                 : (tau == 30 ? 1.0f : 0.0f);
            }
            a2.h[e] = f2bf_rne(v);
        }
        f32x16 tc = {};
        tc = __builtin_amdgcn_mfma_f32_32x32x16_bf16(a2.s, b2.s, tc, 0, 0, 0);
        if (p < kNPairs) {
            D16 u; u.v = tc;
            float* dst = ws + kWsTok + (ihalf * kTB + p) * 16;
            #pragma unroll
            for (int g = 0; g < 4; ++g)
                *(f32x4*)(dst + 4 * g) = u.q[g];
        }
    }
}

// ---------- main kernel ----------
__global__ __launch_bounds__(kBlock, 4) void pin_main(
    const float* __restrict__ x_cont,
    const int*   __restrict__ x_cat,
    const float* __restrict__ exposure,
    const float* __restrict__ cont_W1,
    const float* __restrict__ cont_b1,
    const float* __restrict__ cont_W2,
    const float* __restrict__ cont_b2,
    const float* __restrict__ cat_tables,
    const float* __restrict__ sW3,     // [20]
    const float* __restrict__ out_w,   // [78]
    const float* __restrict__ ws,      // precomputed
    float* __restrict__ out)
{
    // Ej d0..7 packed bf16: [q][b][4 u32], 16B lane stride (conflict-free b128).
    __shared__ __align__(16) unsigned int EldsA[kQ * kM * 4];   // 6144 B
    // Ej d8,d9 packed: [q][b] one u32, 4B lane stride.
    __shared__ __align__(16) unsigned int EldsB[kQ * kM];       // 1536 B
    // tokb in C-reg order, [ih][p][16 f32]; quadrants at +0/16/32/48 B. 10240 B.
    __shared__ __align__(16) float Tok[2 * kTB * 16];
    __shared__ float etab[kM];
    __shared__ unsigned int Zw[4];    // zero words for ihalf1 dummy reads

    const int tid   = threadIdx.x;
    const int lane  = tid & 63;
    const int b     = lane & 31;          // batch row / MFMA col n
    const int ihalf = lane >> 5;          // fragment k-half selector
    const int wv    = __builtin_amdgcn_readfirstlane((int)(tid >> 6));
    const int gb    = blockIdx.x * kM + b;

    if (tid < kM) etab[tid] = 0.0f;
    if (tid == 0) { Zw[0] = 0u; Zw[1] = 0u; Zw[2] = 0u; Zw[3] = 0u; }

    // ---- frag loads from ws (coalesced 16B/lane; identical for all waves) ----
    const u32x4* wsF = (const u32x4*)ws;
    ABu wj0, wj1, bf0, bf1;
    wj0.u = wsF[0 * 64 + lane];
    wj1.u = wsF[1 * 64 + lane];
    bf0.u = wsF[2 * 64 + lane];
    bf1.u = wsF[3 * 64 + lane];

    // ---- Tok fill: 2560 f32 = 640 f32x4, coalesced, conflict-free ----
    {
        const f32x4* src = (const f32x4*)(ws + kWsTok);
        f32x4* dst = (f32x4*)Tok;
        #pragma unroll 1
        for (int t = tid; t < 640; t += kBlock) dst[t] = src[t];
    }

    // ---- Phase A: E table, half-wave units (unit = 2*wv+ihalf in 0..7).
    // Units 0..5: ONE full cont MLP each. Wave 3 (units 6,7): six cat
    // gathers, 3 per half, pipelined (idx loads first, then gathers). ----
    {
        const int unit = (wv << 1) | ihalf;           // uniform per half-wave
        if (unit < kNCont) {
            const int q = unit;                        // cont feature
            const float x = x_cont[gb * kNCont + q];
            f32x2 E2[5];
            #pragma unroll
            for (int dd = 0; dd < 5; ++dd)
                E2[dd] = f32x2{cont_b2[q * kD + 2 * dd],
                               cont_b2[q * kD + 2 * dd + 1]};
            #pragma unroll 4
            for (int h = 0; h < kHid; ++h) {
                const float pre = fmaf(x, cont_W1[q * kHid + h],
                                       cont_b1[q * kHid + h]);
                const float hv  = fmaxf(pre, 0.0f);
                const f32x2 hv2 = {hv, hv};
                const float* w2 = cont_W2 + (q * kHid + h) * kD;
                #pragma unroll
                for (int dd = 0; dd < 5; ++dd)
                    E2[dd] = __builtin_elementwise_fma(
                        hv2, f32x2{w2[2 * dd], w2[2 * dd + 1]}, E2[dd]);
            }
            *(u32x4*)&EldsA[(q * kM + b) * 4] =
                u32x4{pack_trunc(E2[0].x, E2[0].y), pack_trunc(E2[1].x, E2[1].y),
                      pack_trunc(E2[2].x, E2[2].y), pack_trunc(E2[3].x, E2[3].y)};
            EldsB[q * kM + b] = pack_trunc(E2[4].x, E2[4].y);
        } else {
            const int c0 = (unit - kNCont) * 3;        // 0 or 3
            int idxs[3];
            #pragma unroll
            for (int t = 0; t < 3; ++t)
                idxs[t] = x_cat[gb * kNCat + c0 + t];   // issue all idx loads
            #pragma unroll
            for (int t = 0; t < 3; ++t) {
                const int c = c0 + t;
                const int q = kNCont + c;
                const float* src = cat_tables + (c * kNCategories + idxs[t]) * kD;
                f32x2 E2[5];
                #pragma unroll
                for (int dd = 0; dd < 5; ++dd)
                    E2[dd] = f32x2{src[2 * dd], src[2 * dd + 1]};
                *(u32x4*)&EldsA[(q * kM + b) * 4] =
                    u32x4{pack_trunc(E2[0].x, E2[0].y),
                          pack_trunc(E2[1].x, E2[1].y),
                          pack_trunc(E2[2].x, E2[2].y),
                          pack_trunc(E2[3].x, E2[3].y)};
                EldsB[q * kM + b] = pack_trunc(E2[4].x, E2[4].y);
            }
        }
    }
    __syncthreads();

    // ---- Phase B: per pair
    //   d1 = mfma(wj0, [Ej07|Ek07], tokC); d1 = mfma(wj1, [Ej89,Ek89,0..], d1)
    //   hf = pk_relu(pack(d1)) -> d2 = 2 MFMAs -> relu -> out_w-weighted acc ----
    A12 acc;
    #pragma unroll
    for (int h = 0; h < 6; ++h) acc.d[h] = f32x2{0.0f, 0.0f};

    const unsigned int* e0base = EldsA + b * 4;
    const int e0stepJ = ihalf ? 0 : 128;                  // u32/j (row = 512 B)
    const unsigned int* e1base = ihalf ? Zw : (EldsB + b);
    const int e1stepJ = ihalf ? 0 : 32;                   // u32/j (row = 128 B)
    const float* tokBase = Tok + ihalf * (kTB * 16);

    #pragma unroll 1
    for (int ki = 0; ki < 3; ++ki) {
        const int k = __builtin_amdgcn_readfirstlane(cKset[wv * 3 + ki]);
        const unsigned int* pj0 = e0base + (ihalf ? k * 128 : 0);
        const unsigned int* pj1 = e1base;
        const unsigned int ekb  = *(e1base + (ihalf ? 0 : k * 32)); // hoisted /k

        int p = k;                                         // p(j=0) = k
        #pragma unroll 2
        for (int j = 0; j <= k; ++j) {
            ABu e0; e0.u = *(const u32x4*)pj0;   // ih0: Ej d0..7; ih1: Ek d0..7
            const unsigned int ejb = *pj1;       // ih0: Ej d8d9;  ih1: 0
            ABu e1; e1.u = u32x4{ejb, ekb, 0u, 0u};

            const float* tp2 = tokBase + p * 16; // quadrants at +0/+4/+8/+12
            D16 dc;
            dc.q[0] = *(const f32x4*)(tp2);
            dc.q[1] = *(const f32x4*)(tp2 + 4);
            dc.q[2] = *(const f32x4*)(tp2 + 8);
            dc.q[3] = *(const f32x4*)(tp2 + 12);

            __builtin_amdgcn_s_setprio(1);
            f32x16 d1 = dc.v;
            d1 = __builtin_amdgcn_mfma_f32_32x32x16_bf16(wj0.s, e0.s, d1, 0, 0, 0);
            d1 = __builtin_amdgcn_mfma_f32_32x32x16_bf16(wj1.s, e1.s, d1, 0, 0, 0);

            // pack raw d1, then packed-int16 relu (== relu per bf16 half)
            D16 t; t.v = d1;
            ABu hf0, hf1;                              // h1 as layer-2 B-operand
            hf0.w[0] = pk_relu(pack_trunc(t.q[0].x, t.q[0].y));
            hf0.w[1] = pk_relu(pack_trunc(t.q[0].z, t.q[0].w));
            hf0.w[2] = pk_relu(pack_trunc(t.q[1].x, t.q[1].y));
            hf0.w[3] = pk_relu(pack_trunc(t.q[1].z, t.q[1].w));
            hf1.w[0] = pk_relu(pack_trunc(t.q[2].x, t.q[2].y));
            hf1.w[1] = pk_relu(pack_trunc(t.q[2].z, t.q[2].w));
            hf1.w[2] = pk_relu(pack_trunc(t.q[3].x, t.q[3].y));
            hf1.w[3] = pk_relu(pack_trunc(t.q[3].z, t.q[3].w));

            f32x16 d2 = {};
            d2 = __builtin_amdgcn_mfma_f32_32x32x16_bf16(bf0.s, hf0.s, d2, 0, 0, 0);
            d2 = __builtin_amdgcn_mfma_f32_32x32x16_bf16(bf1.s, hf1.s, d2, 0, 0, 0);
            __builtin_amdgcn_s_setprio(0);

            // acc only regs 0..11 (regs 12..15 never read downstream);
            // f32x2 ops -> v_pk_fma_f32 on gfx950
            const float wp = out_w[p];                 // s_load
            const f32x2 wp2 = {wp, wp};
            const f32x2 z2 = {};
            D16 r2; r2.v = d2;
            #pragma unroll
            for (int h = 0; h < 6; ++h) {
                const f32x2 rr = __builtin_elementwise_max(r2.d[h], z2);
                acc.d[h] = __builtin_elementwise_fma(rr, wp2, acc.d[h]);
            }

            pj0 += e0stepJ;
            pj1 += e1stepJ;
            p   += 11 - j;                             // p(j+1) - p(j)
        }
    }

    // ---- epilogue: eta[b] = (1/6)*sum_r sW3[o_r]*acc[r] ----
    float etaL = 0.0f;
    if (ihalf == 0) {       // r=0..11 -> o = 0..3, 8..11, 16..19
        #pragma unroll
        for (int r = 0; r < 12; ++r)
            etaL = fmaf(acc.f[r], sW3[(r & 3) + 8 * (r >> 2)], etaL);
    } else {                // r=0..7 -> o = 4..7, 12..15
        #pragma unroll
        for (int r = 0; r < 8; ++r)
            etaL = fmaf(acc.f[r], sW3[(r & 3) + 8 * (r >> 2) + 4], etaL);
    }
    etaL += __shfl_xor(etaL, 32, 64);   // combine o-halves
    if (ihalf == 0) atomicAdd(&etab[b], etaL);
    __syncthreads();

    if (tid < kM) {
        float eta = etab[tid] * (1.0f / 6.0f) + ws[kWsEta];
        eta = fminf(fmaxf(eta, -20.0f), 20.0f);
        const int ob = blockIdx.x * kM + tid;
        out[ob] = __expf(eta) * exposure[ob];
    }
}

extern "C" void kernel_launch(void* const* d_in, const int* in_sizes, int n_in,
                              void* d_out, int out_size, void* d_ws, size_t ws_size,
                              hipStream_t stream) {
    (void)n_in; (void)out_size; (void)ws_size;
    const float* x_cont     = (const float*)d_in[0];
    const int*   x_cat      = (const int*)  d_in[1];
    const float* exposure   = (const float*)d_in[2];
    const float* cont_W1    = (const float*)d_in[3];
    const float* cont_b1    = (const float*)d_in[4];
    const float* cont_W2    = (const float*)d_in[5];
    const float* cont_b2    = (const float*)d_in[6];
    const float* cat_tables = (const float*)d_in[7];
    const float* tokens     = (const float*)d_in[8];
    const float* sW1        = (const float*)d_in[9];
    const float* sb1        = (const float*)d_in[10];
    const float* sW2        = (const float*)d_in[11];
    const float* sb2        = (const float*)d_in[12];
    const float* sW3        = (const float*)d_in[13];
    const float* sb3        = (const float*)d_in[14];
    const float* out_w      = (const float*)d_in[15];
    const float* out_b      = (const float*)d_in[16];

    float* ws = (float*)d_ws;
    const int B = in_sizes[2];        // exposure is [B]

    pin_setup<<<1, kBlock, 0, stream>>>(
        tokens, sW1, sb1, sW2, sb2, sb3, out_w, out_b, ws);
    pin_main<<<B / kM, kBlock, 0, stream>>>(
        x_cont, x_cat, exposure, cont_W1, cont_b1, cont_W2, cont_b2,
        cat_tables, sW3, out_w, ws, (float*)d_out);
}